// Round 1
// baseline (2954.083 us; speedup 1.0000x reference)
//
#include <hip/hip_runtime.h>

typedef __attribute__((ext_vector_type(8))) short short8;
typedef __attribute__((ext_vector_type(4))) float f32x4;
typedef __attribute__((ext_vector_type(2))) float f32x2;
typedef __attribute__((ext_vector_type(4))) unsigned short us4;

__device__ __forceinline__ unsigned short bf16_of(float f) {
    unsigned u = __builtin_bit_cast(unsigned, f);
    u += 0x7fffu + ((u >> 16) & 1u);   // RNE
    return (unsigned short)(u >> 16);
}
__device__ __forceinline__ float fexp2(float x) { return __builtin_amdgcn_exp2f(x); }
__device__ __forceinline__ float frcp(float x) { return __builtin_amdgcn_rcpf(x); }
__device__ __forceinline__ float sigm(float x) { return frcp(1.f + fexp2(-1.44269504f * x)); }
__device__ __forceinline__ float tanh_f(float x) {
    float e = fexp2(2.88539008f * x);   // e^(2x)
    return 1.f - 2.f * frcp(e + 1.f);
}
__device__ __forceinline__ f32x4 mfma16(short8 a, short8 b, f32x4 c) {
    return __builtin_amdgcn_mfma_f32_16x16x32_bf16(a, b, c, 0, 0, 0);
}

// ---------------------------------------------------------------------------
// Generic fp32 GEMM: C[M,N] = A[M,K] @ B (+bias) (optional relu)
// BT=0: B is [K,N] row-major.  BT=1: B is [N,K] row-major (i.e. use B^T).
// M mult of 64, N mult of 64, K mult of 32.
__global__ __launch_bounds__(256) void gemm_f32(
    const float* __restrict__ A, const float* __restrict__ B,
    const float* __restrict__ bias, float* __restrict__ C,
    int M, int N, int K, int BT, int RELU)
{
    __shared__ float As[64][33];
    __shared__ float Bs[32][68];
    const int tid = threadIdx.x;
    const int tx = tid & 15, ty = tid >> 4;
    const int m0 = blockIdx.y * 64, n0 = blockIdx.x * 64;
    float acc[4][4];
#pragma unroll
    for (int i = 0; i < 4; ++i)
#pragma unroll
        for (int j = 0; j < 4; ++j) acc[i][j] = 0.f;

    for (int k0 = 0; k0 < K; k0 += 32) {
        __syncthreads();
        {   // stage A 64x32
            const int r = tid >> 2, kk = (tid & 3) * 8;
            const float* src = A + (size_t)(m0 + r) * K + k0 + kk;
            f32x4 v0 = *(const f32x4*)src;
            f32x4 v1 = *(const f32x4*)(src + 4);
#pragma unroll
            for (int e = 0; e < 4; ++e) { As[r][kk + e] = v0[e]; As[r][kk + 4 + e] = v1[e]; }
        }
        if (!BT) {  // stage B 32x64
            const int kk = tid >> 3, nn = (tid & 7) * 8;
            const float* src = B + (size_t)(k0 + kk) * N + n0 + nn;
            f32x4 v0 = *(const f32x4*)src;
            f32x4 v1 = *(const f32x4*)(src + 4);
#pragma unroll
            for (int e = 0; e < 4; ++e) { Bs[kk][nn + e] = v0[e]; Bs[kk][nn + 4 + e] = v1[e]; }
        } else {    // B given [N,K]: transpose-stage
            const int n = tid >> 2, kk = (tid & 3) * 8;
            const float* src = B + (size_t)(n0 + n) * K + k0 + kk;
            f32x4 v0 = *(const f32x4*)src;
            f32x4 v1 = *(const f32x4*)(src + 4);
#pragma unroll
            for (int e = 0; e < 4; ++e) { Bs[kk + e][n] = v0[e]; Bs[kk + 4 + e][n] = v1[e]; }
        }
        __syncthreads();
#pragma unroll 8
        for (int k = 0; k < 32; ++k) {
            float a0 = As[ty * 4 + 0][k], a1 = As[ty * 4 + 1][k];
            float a2 = As[ty * 4 + 2][k], a3 = As[ty * 4 + 3][k];
            f32x4 bv = *(const f32x4*)&Bs[k][tx * 4];
#pragma unroll
            for (int j = 0; j < 4; ++j) {
                acc[0][j] += a0 * bv[j]; acc[1][j] += a1 * bv[j];
                acc[2][j] += a2 * bv[j]; acc[3][j] += a3 * bv[j];
            }
        }
    }
    f32x4 bv = {};
    if (bias != nullptr) bv = *(const f32x4*)&bias[n0 + tx * 4];
#pragma unroll
    for (int i = 0; i < 4; ++i) {
        f32x4 res = {};
#pragma unroll
        for (int j = 0; j < 4; ++j) {
            float v = acc[i][j] + bv[j];
            if (RELU) v = fmaxf(v, 0.f);
            res[j] = v;
        }
        *(f32x4*)&C[(size_t)(m0 + ty * 4 + i) * N + n0 + tx * 4] = res;
    }
}

// ---------------------------------------------------------------------------
// si[b,n] = h[b,n,:]·aW[128:256],  sj[b,n] = h[b,n,:]·aW[0:128]
__global__ __launch_bounds__(256) void sisj_kernel(
    const float* __restrict__ h, const float* __restrict__ aW,
    float* __restrict__ si, float* __restrict__ sj)
{
    const int tid = threadIdx.x, lane = tid & 63, w = tid >> 6;
    const int row = blockIdx.x * 4 + w;  // 0..8191
    f32x2 hv = *(const f32x2*)(h + (size_t)row * 128 + lane * 2);
    f32x2 w1 = *(const f32x2*)&aW[lane * 2];
    f32x2 w2 = *(const f32x2*)&aW[128 + lane * 2];
    float sjp = hv[0] * w1[0] + hv[1] * w1[1];
    float sip = hv[0] * w2[0] + hv[1] * w2[1];
#pragma unroll
    for (int o = 32; o > 0; o >>= 1) {
        sjp += __shfl_xor(sjp, o);
        sip += __shfl_xor(sip, o);
    }
    if (lane == 0) { si[row] = sip; sj[row] = sjp; }
}

// ---------------------------------------------------------------------------
// hT[b][d][j] = bf16(h[b][j][d])   (for MFMA B staging)
__global__ __launch_bounds__(256) void transpose_bf16_k(
    const float* __restrict__ h, unsigned short* __restrict__ hT)
{
    __shared__ float t[64][65];
    const int b = blockIdx.z, jt = blockIdx.x, dt = blockIdx.y;
    const int tid = threadIdx.x;
    const int r = tid >> 4, c4 = (tid & 15) * 4;
#pragma unroll
    for (int rr = 0; rr < 4; ++rr) {
        const int j = rr * 16 + r;
        f32x4 v = *(const f32x4*)(h + ((size_t)b * 1024 + jt * 64 + j) * 128 + dt * 64 + c4);
#pragma unroll
        for (int e = 0; e < 4; ++e) t[j][c4 + e] = v[e];
    }
    __syncthreads();
#pragma unroll
    for (int rr = 0; rr < 4; ++rr) {
        const int d = rr * 16 + r;
        us4 o;
#pragma unroll
        for (int e = 0; e < 4; ++e) o[e] = bf16_of(t[c4 + e][d]);
        *(us4*)(hT + ((size_t)b * 128 + dt * 64 + d) * 1024 + jt * 64 + c4) = o;
    }
}

// ---------------------------------------------------------------------------
// out[b,i,d] = sum_j sigmoid(si[i]+sj[j]+ab)*adj[b,i,j]*h[b,j,d]  (opt relu)
// grid (8 i-tiles, 8 b), 256 threads (4 waves). MFMA bf16, fp32 acc.
__global__ __launch_bounds__(256) void gnn_agg(
    const float* __restrict__ adj, const unsigned short* __restrict__ hT,
    const float* __restrict__ si, const float* __restrict__ sj,
    const float* __restrict__ abp, float* __restrict__ out, int RELU)
{
    __shared__ __align__(16) unsigned short Alds[128 * 40];  // [i][j] stride 40
    __shared__ __align__(16) unsigned short Blds[128 * 40];  // [d][j] stride 40
    const int b = blockIdx.y, it = blockIdx.x;
    const int i0 = it * 128;
    const int tid = threadIdx.x, lane = tid & 63, w = tid >> 6;
    const int quad = lane >> 4, col = lane & 15;
    const float ab = abp[0];
    const float* adjb = adj + (size_t)b * 1024 * 1024;
    const unsigned short* hTb = hT + (size_t)b * 128 * 1024;
    const float* sjb = sj + b * 1024;

    f32x4 acc[2][8] = {};
    const int sr = tid >> 1, sh = (tid & 1) * 16;
    const float sii = si[b * 1024 + i0 + sr] + ab;

    for (int j0 = 0; j0 < 1024; j0 += 32) {
        __syncthreads();
        {   // stage A: att tile 128x32 (computed on the fly)
            const float* ar = adjb + (size_t)(i0 + sr) * 1024 + j0 + sh;
            unsigned short* al = Alds + sr * 40 + sh;
#pragma unroll
            for (int q = 0; q < 16; q += 4) {
                f32x4 av = *(const f32x4*)(ar + q);
#pragma unroll
                for (int e = 0; e < 4; ++e) {
                    float s = sigm(sii + sjb[j0 + sh + q + e]) * av[e];
                    al[q + e] = bf16_of(s);
                }
            }
        }
        {   // stage B: hT rows d=0..127, 32 j's
            const unsigned short* bsrc = hTb + (size_t)sr * 1024 + j0 + sh;
            unsigned short* bl = Blds + sr * 40 + sh;
            *(short8*)&bl[0] = *(const short8*)&bsrc[0];
            *(short8*)&bl[8] = *(const short8*)&bsrc[8];
        }
        __syncthreads();
        short8 bfrag[8];
#pragma unroll
        for (int nt = 0; nt < 8; ++nt)
            bfrag[nt] = *(const short8*)&Blds[(nt * 16 + col) * 40 + quad * 8];
#pragma unroll
        for (int mt = 0; mt < 2; ++mt) {
            short8 af = *(const short8*)&Alds[((w * 2 + mt) * 16 + col) * 40 + quad * 8];
#pragma unroll
            for (int nt = 0; nt < 8; ++nt)
                acc[mt][nt] = mfma16(af, bfrag[nt], acc[mt][nt]);
        }
    }
#pragma unroll
    for (int mt = 0; mt < 2; ++mt) {
        const int ibase = i0 + (w * 2 + mt) * 16 + quad * 4;
#pragma unroll
        for (int nt = 0; nt < 8; ++nt) {
            const int d = nt * 16 + col;
#pragma unroll
            for (int r = 0; r < 4; ++r) {
                float v = acc[mt][nt][r];
                if (RELU) v = fmaxf(v, 0.f);
                out[((size_t)b * 1024 + ibase + r) * 128 + d] = v;
            }
        }
    }
}

// ---------------------------------------------------------------------------
// xw[t][r][b] = tmp[b*1024+t][r] + bih[r] + bhh[r]
__global__ __launch_bounds__(256) void permute_xw(
    const float* __restrict__ tmp, const float* __restrict__ bih,
    const float* __restrict__ bhh, float* __restrict__ xw)
{
    const int idx = blockIdx.x * 256 + threadIdx.x;  // < 4194304
    const int bb = idx & 7;
    const int r = (idx >> 3) & 511;
    const int t = idx >> 12;
    xw[idx] = tmp[((size_t)bb * 1024 + t) * 512 + r] + bih[r] + bhh[r];
}

// ---------------------------------------------------------------------------
// Persistent single-workgroup LSTM layer.
// xw: [1024][512][8] precomputed x@Wih^T + bih + bhh.  Whh: [512][128] fp32.
// out: [8][1024][128] hidden states (fp32).
// 512 threads = 8 waves; wave w owns gate rows {g*128 + w*16 .. +16} for all 4
// gates g -> epilogue is wave-local. Whh held in regs as bf16 A-fragments.
__global__ __launch_bounds__(512) void lstm_kernel(
    const float* __restrict__ xw, const float* __restrict__ Whh,
    float* __restrict__ out)
{
    __shared__ __align__(16) unsigned short H[2][16 * 136];  // [buf][b(16)][k(128)+pad8]
    const int tid = threadIdx.x;
    const int lane = tid & 63;
    const int w = tid >> 6;        // wave 0..7
    const int quad = lane >> 4;    // 0..3
    const int col = lane & 15;     // batch (real if <8)

    for (int i = tid; i < 2 * 16 * 136; i += 512) (&H[0][0])[i] = 0;

    // A-fragments: afr[g][c] covers rows g*128 + w*16 + (lane&15), k = c*32+quad*8..+8
    short8 afr[4][4];
#pragma unroll
    for (int g = 0; g < 4; ++g) {
        const int row = g * 128 + w * 16 + col;
#pragma unroll
        for (int c = 0; c < 4; ++c) {
            const float* src = Whh + row * 128 + c * 32 + quad * 8;
            short8 v;
#pragma unroll
            for (int j = 0; j < 8; ++j) v[j] = (short)bf16_of(src[j]);
            afr[g][c] = v;
        }
    }
    float cst[4] = {0.f, 0.f, 0.f, 0.f};
    const int hbase = w * 16 + quad * 4;   // hidx base for this lane
    __syncthreads();

    for (int t = 0; t < 1024; ++t) {
        const int cur = t & 1;
        // prefetch xw for this step (issued before MFMAs)
        float xwv[4][4];
#pragma unroll
        for (int g = 0; g < 4; ++g)
#pragma unroll
            for (int i = 0; i < 4; ++i) {
                const int r = g * 128 + hbase + i;
                xwv[g][i] = (col < 8) ? xw[(t * 512 + r) * 8 + col] : 0.f;
            }
        // B-fragments from LDS h
        short8 bfr[4];
#pragma unroll
        for (int c = 0; c < 4; ++c)
            bfr[c] = *(const short8*)&H[cur][col * 136 + c * 32 + quad * 8];
        f32x4 acc[4] = {};
#pragma unroll
        for (int c = 0; c < 4; ++c)
#pragma unroll
            for (int g = 0; g < 4; ++g)
                acc[g] = mfma16(afr[g][c], bfr[c], acc[g]);
        // epilogue: gates i,f,g,o = acc[0..3] + xw
        float hv[4];
#pragma unroll
        for (int i = 0; i < 4; ++i) {
            float ig = sigm(acc[0][i] + xwv[0][i]);
            float fg = sigm(acc[1][i] + xwv[1][i]);
            float gg = tanh_f(acc[2][i] + xwv[2][i]);
            float og = sigm(acc[3][i] + xwv[3][i]);
            float c2 = fg * cst[i] + ig * gg;
            cst[i] = c2;
            hv[i] = og * tanh_f(c2);
        }
        if (col < 8) {
            unsigned short* dst = &H[cur ^ 1][col * 136 + hbase];
#pragma unroll
            for (int i = 0; i < 4; ++i) dst[i] = bf16_of(hv[i]);
            f32x4 res = {hv[0], hv[1], hv[2], hv[3]};
            *(f32x4*)(out + ((size_t)col * 1024 + t) * 128 + hbase) = res;
        }
        __syncthreads();
    }
}

// ---------------------------------------------------------------------------
extern "C" void kernel_launch(void* const* d_in, const int* in_sizes, int n_in,
                              void* d_out, int out_size, void* d_ws, size_t ws_size,
                              hipStream_t stream)
{
    (void)in_sizes; (void)n_in; (void)out_size; (void)ws_size;
    const float* nf    = (const float*)d_in[0];
    const float* adj   = (const float*)d_in[1];
    const float* g1W   = (const float*)d_in[3];
    const float* g1b   = (const float*)d_in[4];
    const float* g1aW  = (const float*)d_in[5];
    const float* g1ab  = (const float*)d_in[6];
    const float* g2W   = (const float*)d_in[7];
    const float* g2b   = (const float*)d_in[8];
    const float* g2aW  = (const float*)d_in[9];
    const float* g2ab  = (const float*)d_in[10];
    const float* g3W   = (const float*)d_in[11];
    const float* g3b   = (const float*)d_in[12];
    const float* g3aW  = (const float*)d_in[13];
    const float* g3ab  = (const float*)d_in[14];
    const float* l0Wih = (const float*)d_in[15];
    const float* l0Whh = (const float*)d_in[16];
    const float* l0bih = (const float*)d_in[17];
    const float* l0bhh = (const float*)d_in[18];
    const float* l1Wih = (const float*)d_in[19];
    const float* l1Whh = (const float*)d_in[20];
    const float* l1bih = (const float*)d_in[21];
    const float* l1bhh = (const float*)d_in[22];
    const float* opW1 = (const float*)d_in[23];
    const float* opb1 = (const float*)d_in[24];
    const float* opW2 = (const float*)d_in[25];
    const float* opb2 = (const float*)d_in[26];
    const float* paW1 = (const float*)d_in[27];
    const float* pab1 = (const float*)d_in[28];
    const float* paW2 = (const float*)d_in[29];
    const float* pab2 = (const float*)d_in[30];
    const float* skW1 = (const float*)d_in[31];
    const float* skb1 = (const float*)d_in[32];
    const float* skW2 = (const float*)d_in[33];
    const float* skb2 = (const float*)d_in[34];
    const float* noW1 = (const float*)d_in[35];
    const float* nob1 = (const float*)d_in[36];
    const float* noW2 = (const float*)d_in[37];
    const float* nob2 = (const float*)d_in[38];

    float* out = (float*)d_out;
    float* ws = (float*)d_ws;
    float* bufH  = ws;                     // 1048576
    float* bufX  = ws + 1048576;           // 1048576
    float* bufH3 = ws + 2097152;           // 1048576
    unsigned short* bufT = (unsigned short*)(ws + 3145728);  // 1048576 shorts
    float* siB = ws + 3670016;             // 8192
    float* sjB = ws + 3678208;             // 8192
    float* tmp = ws + 3686400;             // 4194304
    float* xw  = ws + 7880704;             // 4194304 (end: 48.3 MB)

    auto gemm = [&](const float* A, const float* B, const float* bias, float* C,
                    int M, int N, int K, int BT, int RELU) {
        dim3 g(N / 64, M / 64);
        gemm_f32<<<g, dim3(256), 0, stream>>>(A, B, bias, C, M, N, K, BT, RELU);
    };

    // ---- GNN layer 1 (din=64, relu)
    gemm(nf, g1W, g1b, bufH, 8192, 128, 64, 0, 0);
    sisj_kernel<<<2048, 256, 0, stream>>>(bufH, g1aW, siB, sjB);
    transpose_bf16_k<<<dim3(16, 2, 8), 256, 0, stream>>>(bufH, bufT);
    gnn_agg<<<dim3(8, 8), 256, 0, stream>>>(adj, bufT, siB, sjB, g1ab, bufX, 1);
    // ---- GNN layer 2 (relu)
    gemm(bufX, g2W, g2b, bufH, 8192, 128, 128, 0, 0);
    sisj_kernel<<<2048, 256, 0, stream>>>(bufH, g2aW, siB, sjB);
    transpose_bf16_k<<<dim3(16, 2, 8), 256, 0, stream>>>(bufH, bufT);
    gnn_agg<<<dim3(8, 8), 256, 0, stream>>>(adj, bufT, siB, sjB, g2ab, bufX, 1);
    // ---- GNN layer 3 (no relu) -> bufH3
    gemm(bufX, g3W, g3b, bufH, 8192, 128, 128, 0, 0);
    sisj_kernel<<<2048, 256, 0, stream>>>(bufH, g3aW, siB, sjB);
    transpose_bf16_k<<<dim3(16, 2, 8), 256, 0, stream>>>(bufH, bufT);
    gnn_agg<<<dim3(8, 8), 256, 0, stream>>>(adj, bufT, siB, sjB, g3ab, bufH3, 0);

    // ---- LSTM layer 0: lo0 = bufX
    gemm(bufH3, l0Wih, nullptr, tmp, 8192, 512, 128, 1, 0);
    permute_xw<<<16384, 256, 0, stream>>>(tmp, l0bih, l0bhh, xw);
    lstm_kernel<<<1, 512, 0, stream>>>(xw, l0Whh, bufX);
    // ---- LSTM layer 1: lo1 = tmp
    gemm(bufX, l1Wih, nullptr, tmp, 8192, 512, 128, 1, 0);
    permute_xw<<<16384, 256, 0, stream>>>(tmp, l1bih, l1bhh, xw);
    lstm_kernel<<<1, 512, 0, stream>>>(xw, l1Whh, tmp);

    // ---- heads (op, pa, sk from lo1=tmp; no from h3=bufH3)
    gemm(tmp, opW1, opb1, bufH, 8192, 128, 128, 0, 1);
    gemm(bufH, opW2, opb2, out + 0, 8192, 64, 128, 0, 0);
    gemm(tmp, paW1, pab1, bufH, 8192, 128, 128, 0, 1);
    gemm(bufH, paW2, pab2, out + 524288, 8192, 256, 128, 0, 0);
    gemm(tmp, skW1, skb1, bufH, 8192, 128, 128, 0, 1);
    gemm(bufH, skW2, skb2, out + 2621440, 8192, 128, 128, 0, 0);
    gemm(bufH3, noW1, nob1, bufH, 8192, 128, 128, 0, 1);
    gemm(bufH, noW2, nob2, out + 3670016, 8192, 64, 128, 0, 0);
}